// Round 1
// baseline (3131.251 us; speedup 1.0000x reference)
//
#include <hip/hip_runtime.h>
#include <math.h>

#define NB 16
#define L 256
#define H 128
#define HID 128
#define LAMF 20.0f
#define EPSF 1e-8f
#define NITER 20

// ---------------------------------------------------------------------------
// K1: scores = tanh(f @ W1 + b1) @ W2 + b2
// grid 16384 blocks x 256 thr; each block: 64 arcs x 128 hidden, K=128 in 4x32
// ---------------------------------------------------------------------------
__global__ __launch_bounds__(256) void k_scores(
    const float* __restrict__ f, const float* __restrict__ W1,
    const float* __restrict__ b1, const float* __restrict__ W2,
    const float* __restrict__ b2, float* __restrict__ scores)
{
    __shared__ float As[32][68];   // As[k][m] transposed, row = 272B (16B mult)
    __shared__ float Bs[32][132];  // Bs[k][n], row = 528B (16B mult)
    const int tid = threadIdx.x;
    const int tx = tid & 31;       // col group: cols tx*4..tx*4+3
    const int ty = tid >> 5;       // row group: rows ty*8..ty*8+7
    const long m0 = (long)blockIdx.x * 64;

    float acc[8][4];
#pragma unroll
    for (int i = 0; i < 8; i++)
#pragma unroll
        for (int c = 0; c < 4; c++) acc[i][c] = 0.f;

    for (int kc = 0; kc < H; kc += 32) {
        // stage A tile (64 rows x 32 k), coalesced over k
        {
            const int k = tid & 31, mb = tid >> 5;
#pragma unroll
            for (int r = 0; r < 8; r++) {
                int m = mb + r * 8;
                As[k][m] = f[(m0 + m) * H + kc + k];
            }
        }
        // stage B tile (32 k x 128 n), coalesced over n
        {
#pragma unroll
            for (int r = 0; r < 16; r++) {
                int idx = r * 256 + tid;
                int k = idx >> 7, n = idx & 127;
                Bs[k][n] = W1[(kc + k) * HID + n];
            }
        }
        __syncthreads();
#pragma unroll
        for (int k = 0; k < 32; k++) {
            float4 a0 = *(const float4*)&As[k][ty * 8];
            float4 a1 = *(const float4*)&As[k][ty * 8 + 4];
            float4 bv = *(const float4*)&Bs[k][tx * 4];
            float av[8] = {a0.x, a0.y, a0.z, a0.w, a1.x, a1.y, a1.z, a1.w};
            float bb[4] = {bv.x, bv.y, bv.z, bv.w};
#pragma unroll
            for (int i = 0; i < 8; i++)
#pragma unroll
                for (int c = 0; c < 4; c++)
                    acc[i][c] = fmaf(av[i], bb[c], acc[i][c]);
        }
        __syncthreads();
    }
    // epilogue: tanh + dot with W2, reduce over the 32 col-groups (lanes tx)
    float part[8];
#pragma unroll
    for (int i = 0; i < 8; i++) part[i] = 0.f;
#pragma unroll
    for (int c = 0; c < 4; c++) {
        int col = tx * 4 + c;
        float b1v = b1[col], w2v = W2[col];
#pragma unroll
        for (int i = 0; i < 8; i++) {
            float hv = tanhf(acc[i][c] + b1v);
            part[i] = fmaf(hv, w2v, part[i]);
        }
    }
#pragma unroll
    for (int off = 16; off >= 1; off >>= 1)
#pragma unroll
        for (int i = 0; i < 8; i++)
            part[i] += __shfl_xor(part[i], off, 64);
    if (tx == 0) {
        float b2v = b2[0];
#pragma unroll
        for (int i = 0; i < 8; i++) {
            int row = ty * 8 + i;
            scores[m0 + row] = part[i] + b2v;
        }
    }
}

// ---------------------------------------------------------------------------
// K2: C[s,i,j] = dot128(f[s,i,j,:], f[s,j,i,:])  — symmetric, compute i<=j
// grid 4096 (s,i), 256 thr = 4 waves, one dot per wave
// ---------------------------------------------------------------------------
__global__ __launch_bounds__(256) void k_cost(
    const float* __restrict__ f, float* __restrict__ C)
{
    const int bid = blockIdx.x;
    const int s = bid >> 8, i = bid & 255;
    const int wave = threadIdx.x >> 6, lane = threadIdx.x & 63;
    const long base_i = ((long)(s * L + i)) * L;
    for (int j4 = i; j4 < L; j4 += 4) {
        int j = j4 + wave;
        if (j < L) {
            const float2 x = *(const float2*)&f[(base_i + j) * (long)H + lane * 2];
            const float2 y = *(const float2*)&f[(((long)(s * L + j)) * L + i) * (long)H + lane * 2];
            float d = fmaf(x.x, y.x, x.y * y.y);
#pragma unroll
            for (int off = 32; off >= 1; off >>= 1) d += __shfl_xor(d, off, 64);
            if (lane == 0) {
                C[base_i + j] = d;
                C[((long)(s * L + j)) * L + i] = d;
            }
        }
    }
}

// ---------------------------------------------------------------------------
// K3: per-sample max |C|
// ---------------------------------------------------------------------------
__global__ __launch_bounds__(256) void k_absmax(
    const float* __restrict__ C, float* __restrict__ maxabs)
{
    __shared__ float red[256];
    const int s = blockIdx.x, tid = threadIdx.x;
    const float* Cp = C + (long)s * L * L;
    float m = 0.f;
    for (int idx = tid; idx < L * L; idx += 256) m = fmaxf(m, fabsf(Cp[idx]));
    red[tid] = m;
    __syncthreads();
    for (int o = 128; o >= 1; o >>= 1) {
        if (tid < o) red[tid] = fmaxf(red[tid], red[tid + o]);
        __syncthreads();
    }
    if (tid == 0) maxabs[s] = red[0];
}

// ---------------------------------------------------------------------------
// K4: Kmat = exp(-LAM*Cn), KM = Kmat*Cn   (Cn = C/(maxabs+EPS))
// ---------------------------------------------------------------------------
__global__ __launch_bounds__(512) void k_kmat(
    const float* __restrict__ C, const float* __restrict__ maxabs,
    float* __restrict__ Km, float* __restrict__ KMm)
{
    long idx = (long)blockIdx.x * blockDim.x + threadIdx.x;
    const long tot = (long)NB * L * L;
    for (; idx < tot; idx += (long)gridDim.x * blockDim.x) {
        int s = (int)(idx >> 16);
        float cn = C[idx] / (maxabs[s] + EPSF);
        float kv = __expf(-LAMF * cn);
        Km[idx] = kv;
        KMm[idx] = kv * cn;
    }
}

// ---------------------------------------------------------------------------
// K5: r = softmax(scores row), c = (head+EPS)/rowsum — one block per (s,row)
// ---------------------------------------------------------------------------
__global__ __launch_bounds__(256) void k_rc(
    const float* __restrict__ scores, const float* __restrict__ head,
    float* __restrict__ R, float* __restrict__ Cd)
{
    __shared__ float red[256];
    const long base = (long)blockIdx.x * L;
    const int t = threadIdx.x;
    float sc = scores[base + t];
    red[t] = sc;
    __syncthreads();
    for (int o = 128; o >= 1; o >>= 1) {
        if (t < o) red[t] = fmaxf(red[t], red[t + o]);
        __syncthreads();
    }
    float mx = red[0];
    __syncthreads();
    float e = __expf(sc - mx);
    red[t] = e;
    __syncthreads();
    for (int o = 128; o >= 1; o >>= 1) {
        if (t < o) red[t] += red[t + o];
        __syncthreads();
    }
    float es = red[0];
    __syncthreads();
    R[base + t] = e / es;
    float hv = head[base + t] + EPSF;
    red[t] = hv;
    __syncthreads();
    for (int o = 128; o >= 1; o >>= 1) {
        if (t < o) red[t] += red[t + o];
        __syncthreads();
    }
    float hs = red[0];
    Cd[base + t] = hv / hs;
}

// ---------------------------------------------------------------------------
// K6: Sinkhorn. One block per (sample, 16-column chunk); 512 threads.
// Column j <-> row-problem (s, j0+j). All matvecs use K^T@x = K@x (K symm).
// U/T ping-pong in LDS [b][j] (stride 16); K read as float4 from L1/L2.
// Thread tile: 4 a's x 2 j's.
// ---------------------------------------------------------------------------
__global__ __launch_bounds__(512) void k_sink(
    const float* __restrict__ Km, const float* __restrict__ KMm,
    const float* __restrict__ R, const float* __restrict__ Cd,
    float* __restrict__ lossbuf)
{
    __shared__ float Uc[L * 16];
    __shared__ float Tc[L * 16];
    __shared__ float red[512];
    const int bid = blockIdx.x;
    const int s = bid >> 4;
    const int j0 = (bid & 15) * 16;
    const float* Kp  = Km  + (long)s * L * L;
    const float* KMp = KMm + (long)s * L * L;
    const float* Rp  = R  + (long)s * L * L + (long)j0 * L;
    const float* Cp  = Cd + (long)s * L * L + (long)j0 * L;

    const int tid = threadIdx.x;
    const int atile = tid >> 7;       // 0..3
    const int t = tid & 127;
    const int ta = t & 15;            // 0..15
    const int jh = t >> 4;            // 0..7
    const int ab = atile * 64 + ta * 4;  // 4 a's: ab..ab+3
    const int jb = jh * 2;               // 2 j's: jb, jb+1

    for (int idx = tid; idx < L * 16; idx += 512) Uc[idx] = 1.0f / L;
    __syncthreads();

    float acc[4][2];
    auto gemm = [&](const float* __restrict__ M, const float* __restrict__ S) {
#pragma unroll
        for (int ai = 0; ai < 4; ai++) { acc[ai][0] = 0.f; acc[ai][1] = 0.f; }
#pragma unroll 4
        for (int b = 0; b < L; b++) {
            float4 kv = *(const float4*)&M[b * L + ab];
            float s0 = S[b * 16 + jb];
            float s1 = S[b * 16 + jb + 1];
            acc[0][0] = fmaf(kv.x, s0, acc[0][0]); acc[0][1] = fmaf(kv.x, s1, acc[0][1]);
            acc[1][0] = fmaf(kv.y, s0, acc[1][0]); acc[1][1] = fmaf(kv.y, s1, acc[1][1]);
            acc[2][0] = fmaf(kv.z, s0, acc[2][0]); acc[2][1] = fmaf(kv.z, s1, acc[2][1]);
            acc[3][0] = fmaf(kv.w, s0, acc[3][0]); acc[3][1] = fmaf(kv.w, s1, acc[3][1]);
        }
    };

    float lp = 0.f;
    for (int it = 0; it <= NITER; it++) {
        // P = K^T @ U ; T = c/(P+eps)  (iterations: inner Q; final: V)
        gemm(Kp, Uc);
#pragma unroll
        for (int cj = 0; cj < 2; cj++) {
            float4 cv = *(const float4*)&Cp[(jb + cj) * L + ab];
            float cva[4] = {cv.x, cv.y, cv.z, cv.w};
#pragma unroll
            for (int ai = 0; ai < 4; ai++)
                Tc[(ab + ai) * 16 + jb + cj] = cva[ai] / (acc[ai][cj] + EPSF);
        }
        __syncthreads();
        if (it < NITER) {
            // U = r/(K @ T + eps)
            gemm(Kp, Tc);
#pragma unroll
            for (int cj = 0; cj < 2; cj++) {
                float4 rv = *(const float4*)&Rp[(jb + cj) * L + ab];
                float rva[4] = {rv.x, rv.y, rv.z, rv.w};
#pragma unroll
                for (int ai = 0; ai < 4; ai++)
                    Uc[(ab + ai) * 16 + jb + cj] = rva[ai] / (acc[ai][cj] + EPSF);
            }
            __syncthreads();
        } else {
            // W = KM @ V ; lp += sum U*W
            gemm(KMp, Tc);
#pragma unroll
            for (int cj = 0; cj < 2; cj++)
#pragma unroll
                for (int ai = 0; ai < 4; ai++)
                    lp += Uc[(ab + ai) * 16 + jb + cj] * acc[ai][cj];
        }
    }
    red[tid] = lp;
    __syncthreads();
    for (int o = 256; o >= 1; o >>= 1) {
        if (tid < o) red[tid] += red[tid + o];
        __syncthreads();
    }
    if (tid == 0) lossbuf[bid] = red[0];
}

// ---------------------------------------------------------------------------
// K7: final sum of 256 block partials -> wloss
// ---------------------------------------------------------------------------
__global__ __launch_bounds__(256) void k_final(
    const float* __restrict__ lossbuf, float* __restrict__ out)
{
    __shared__ float red[256];
    int t = threadIdx.x;
    red[t] = lossbuf[t];
    __syncthreads();
    for (int o = 128; o >= 1; o >>= 1) {
        if (t < o) red[t] += red[t + o];
        __syncthreads();
    }
    if (t == 0) out[0] = red[0];
}

// ---------------------------------------------------------------------------
// ws layout (floats): C[1M] | Km[1M] | KM[1M] | R[1M] | Cd[1M] | maxabs[64] |
//                     lossbuf[256]   -> ~20 MB total
// ---------------------------------------------------------------------------
extern "C" void kernel_launch(void* const* d_in, const int* in_sizes, int n_in,
                              void* d_out, int out_size, void* d_ws, size_t ws_size,
                              hipStream_t stream)
{
    const float* f    = (const float*)d_in[0];
    const float* head = (const float*)d_in[1];
    const float* W1   = (const float*)d_in[2];
    const float* b1   = (const float*)d_in[3];
    const float* W2   = (const float*)d_in[4];
    const float* b2   = (const float*)d_in[5];
    float* scores = (float*)d_out;                 // 16*256*256
    float* wloss  = scores + (long)NB * L * L;     // + 1

    float* ws      = (float*)d_ws;
    float* C       = ws;
    float* Km      = ws + 1 * 1048576;
    float* KMm     = ws + 2 * 1048576;
    float* R       = ws + 3 * 1048576;
    float* Cd      = ws + 4 * 1048576;
    float* maxabs  = ws + 5 * 1048576;
    float* lossbuf = maxabs + 64;

    k_scores<<<16384, 256, 0, stream>>>(f, W1, b1, W2, b2, scores);
    k_cost  <<<4096,  256, 0, stream>>>(f, C);
    k_absmax<<<NB,    256, 0, stream>>>(C, maxabs);
    k_kmat  <<<2048,  512, 0, stream>>>(C, maxabs, Km, KMm);
    k_rc    <<<NB * L, 256, 0, stream>>>(scores, head, R, Cd);
    k_sink  <<<NB * 16, 512, 0, stream>>>(Km, KMm, R, Cd, lossbuf);
    k_final <<<1, 256, 0, stream>>>(lossbuf, wloss);
}

// Round 2
// 1736.942 us; speedup vs baseline: 1.8027x; 1.8027x over previous
//
#include <hip/hip_runtime.h>
#include <math.h>

#define NB 16
#define L 256
#define H 128
#define HID 128
#define LAMF 20.0f
#define EPSF 1e-8f
#define NITER 20

// async global->LDS, 16B per lane
#define GLL16(gp, lp) __builtin_amdgcn_global_load_lds( \
    (const __attribute__((address_space(1))) unsigned int*)(gp), \
    (__attribute__((address_space(3))) unsigned int*)(lp), 16, 0, 0)
// s_waitcnt encodings (gfx9): vmcnt low [3:0], exp [6:4], lgkm [11:8], vmcnt hi [15:14]
#define WAITVM2() __builtin_amdgcn_s_waitcnt(0x0F72)  // vmcnt(2), lgkm/exp nowait
#define WAITVM0() __builtin_amdgcn_s_waitcnt(0x0F70)  // vmcnt(0)
#define WAITLGKM0() __builtin_amdgcn_s_waitcnt(0xC07F) // lgkmcnt(0), vm/exp nowait

// ---------------------------------------------------------------------------
// K1: scores = tanh(f @ W1 + b1) @ W2 + b2   (unchanged)
// ---------------------------------------------------------------------------
__global__ __launch_bounds__(256) void k_scores(
    const float* __restrict__ f, const float* __restrict__ W1,
    const float* __restrict__ b1, const float* __restrict__ W2,
    const float* __restrict__ b2, float* __restrict__ scores)
{
    __shared__ float As[32][68];
    __shared__ float Bs[32][132];
    const int tid = threadIdx.x;
    const int tx = tid & 31;
    const int ty = tid >> 5;
    const long m0 = (long)blockIdx.x * 64;

    float acc[8][4];
#pragma unroll
    for (int i = 0; i < 8; i++)
#pragma unroll
        for (int c = 0; c < 4; c++) acc[i][c] = 0.f;

    for (int kc = 0; kc < H; kc += 32) {
        {
            const int k = tid & 31, mb = tid >> 5;
#pragma unroll
            for (int r = 0; r < 8; r++) {
                int m = mb + r * 8;
                As[k][m] = f[(m0 + m) * H + kc + k];
            }
        }
        {
#pragma unroll
            for (int r = 0; r < 16; r++) {
                int idx = r * 256 + tid;
                int k = idx >> 7, n = idx & 127;
                Bs[k][n] = W1[(kc + k) * HID + n];
            }
        }
        __syncthreads();
#pragma unroll
        for (int k = 0; k < 32; k++) {
            float4 a0 = *(const float4*)&As[k][ty * 8];
            float4 a1 = *(const float4*)&As[k][ty * 8 + 4];
            float4 bv = *(const float4*)&Bs[k][tx * 4];
            float av[8] = {a0.x, a0.y, a0.z, a0.w, a1.x, a1.y, a1.z, a1.w};
            float bb[4] = {bv.x, bv.y, bv.z, bv.w};
#pragma unroll
            for (int i = 0; i < 8; i++)
#pragma unroll
                for (int c = 0; c < 4; c++)
                    acc[i][c] = fmaf(av[i], bb[c], acc[i][c]);
        }
        __syncthreads();
    }
    float part[8];
#pragma unroll
    for (int i = 0; i < 8; i++) part[i] = 0.f;
#pragma unroll
    for (int c = 0; c < 4; c++) {
        int col = tx * 4 + c;
        float b1v = b1[col], w2v = W2[col];
#pragma unroll
        for (int i = 0; i < 8; i++) {
            float hv = tanhf(acc[i][c] + b1v);
            part[i] = fmaf(hv, w2v, part[i]);
        }
    }
#pragma unroll
    for (int off = 16; off >= 1; off >>= 1)
#pragma unroll
        for (int i = 0; i < 8; i++)
            part[i] += __shfl_xor(part[i], off, 64);
    if (tx == 0) {
        float b2v = b2[0];
#pragma unroll
        for (int i = 0; i < 8; i++) {
            int row = ty * 8 + i;
            scores[m0 + row] = part[i] + b2v;
        }
    }
}

// ---------------------------------------------------------------------------
// K2: C[s,i,j] = dot128(f[s,i,j,:], f[s,j,i,:])  (unchanged)
// ---------------------------------------------------------------------------
__global__ __launch_bounds__(256) void k_cost(
    const float* __restrict__ f, float* __restrict__ C)
{
    const int bid = blockIdx.x;
    const int s = bid >> 8, i = bid & 255;
    const int wave = threadIdx.x >> 6, lane = threadIdx.x & 63;
    const long base_i = ((long)(s * L + i)) * L;
    for (int j4 = i; j4 < L; j4 += 4) {
        int j = j4 + wave;
        if (j < L) {
            const float2 x = *(const float2*)&f[(base_i + j) * (long)H + lane * 2];
            const float2 y = *(const float2*)&f[(((long)(s * L + j)) * L + i) * (long)H + lane * 2];
            float d = fmaf(x.x, y.x, x.y * y.y);
#pragma unroll
            for (int off = 32; off >= 1; off >>= 1) d += __shfl_xor(d, off, 64);
            if (lane == 0) {
                C[base_i + j] = d;
                C[((long)(s * L + j)) * L + i] = d;
            }
        }
    }
}

// ---------------------------------------------------------------------------
// K3: per-sample max |C|  (unchanged)
// ---------------------------------------------------------------------------
__global__ __launch_bounds__(256) void k_absmax(
    const float* __restrict__ C, float* __restrict__ maxabs)
{
    __shared__ float red[256];
    const int s = blockIdx.x, tid = threadIdx.x;
    const float* Cp = C + (long)s * L * L;
    float m = 0.f;
    for (int idx = tid; idx < L * L; idx += 256) m = fmaxf(m, fabsf(Cp[idx]));
    red[tid] = m;
    __syncthreads();
    for (int o = 128; o >= 1; o >>= 1) {
        if (tid < o) red[tid] = fmaxf(red[tid], red[tid + o]);
        __syncthreads();
    }
    if (tid == 0) maxabs[s] = red[0];
}

// ---------------------------------------------------------------------------
// K4: Kmat = exp(-LAM*Cn), KM = Kmat*Cn  (unchanged)
// ---------------------------------------------------------------------------
__global__ __launch_bounds__(512) void k_kmat(
    const float* __restrict__ C, const float* __restrict__ maxabs,
    float* __restrict__ Km, float* __restrict__ KMm)
{
    long idx = (long)blockIdx.x * blockDim.x + threadIdx.x;
    const long tot = (long)NB * L * L;
    for (; idx < tot; idx += (long)gridDim.x * blockDim.x) {
        int s = (int)(idx >> 16);
        float cn = C[idx] / (maxabs[s] + EPSF);
        float kv = __expf(-LAMF * cn);
        Km[idx] = kv;
        KMm[idx] = kv * cn;
    }
}

// ---------------------------------------------------------------------------
// K5: r = softmax(scores row), c = (head+EPS)/rowsum  (unchanged)
// ---------------------------------------------------------------------------
__global__ __launch_bounds__(256) void k_rc(
    const float* __restrict__ scores, const float* __restrict__ head,
    float* __restrict__ R, float* __restrict__ Cd)
{
    __shared__ float red[256];
    const long base = (long)blockIdx.x * L;
    const int t = threadIdx.x;
    float sc = scores[base + t];
    red[t] = sc;
    __syncthreads();
    for (int o = 128; o >= 1; o >>= 1) {
        if (t < o) red[t] = fmaxf(red[t], red[t + o]);
        __syncthreads();
    }
    float mx = red[0];
    __syncthreads();
    float e = __expf(sc - mx);
    red[t] = e;
    __syncthreads();
    for (int o = 128; o >= 1; o >>= 1) {
        if (t < o) red[t] += red[t + o];
        __syncthreads();
    }
    float es = red[0];
    __syncthreads();
    R[base + t] = e / es;
    float hv = head[base + t] + EPSF;
    red[t] = hv;
    __syncthreads();
    for (int o = 128; o >= 1; o >>= 1) {
        if (t < o) red[t] += red[t + o];
        __syncthreads();
    }
    float hs = red[0];
    Cd[base + t] = hv / hs;
}

// ---------------------------------------------------------------------------
// K6: Sinkhorn v2 — wave-private async K staging, zero intra-pass barriers.
// Grid 256 = (sample, 16-col chunk), 512 thr (8 waves). Wave w owns K columns
// [32w,32w+32). K staged per 16-row tile into per-wave LDS double buffers via
// global_load_lds; sync via own vmcnt only. U/T in LDS, stride 16, XOR-pair
// swizzle (j ^ (b&14)) -> conflict-free ds_read_b64. 1 barrier per pass.
// Thread tile: 4 a's x 2 j's. LDS = 32K (Kw) + 16K (Uc) + 16K (Tc) = 64KB.
// ---------------------------------------------------------------------------
__global__ __launch_bounds__(512) void k_sink(
    const float* __restrict__ Km, const float* __restrict__ KMm,
    const float* __restrict__ R, const float* __restrict__ Cd,
    float* __restrict__ lossbuf)
{
    __shared__ __align__(128) float Kw[8 * 2 * 512];   // [wave][buf][16 rows x 32 cols]
    __shared__ __align__(128) float Uc[4096];
    __shared__ __align__(128) float Tc[4096];

    const int bid = blockIdx.x;
    const int s = bid >> 4;
    const int j0 = (bid & 15) * 16;
    const float* Kp  = Km  + (long)s * 65536;
    const float* KMp = KMm + (long)s * 65536;
    const float* Rp  = R  + (long)s * 65536 + (long)j0 * L;
    const float* Cp  = Cd + (long)s * 65536 + (long)j0 * L;

    const int tid  = threadIdx.x;
    const int w    = tid >> 6;
    const int lane = tid & 63;
    const int ta   = lane & 7;    // 0..7  -> a quad
    const int jh   = lane >> 3;   // 0..7  -> j pair
    const int ab   = w * 32 + ta * 4;
    const int jb   = jh * 2;

    // staging offsets: wave tile region is 2KB ([16 rows][128B])
    const int o0 = lane * 16;          // chunk 0 byte offset
    const int o1 = (64 + lane) * 16;   // chunk 1
    char* lbase = (char*)&Kw[w * 1024];
    const int gcol = w * 128;          // byte column offset of this wave's slice

    // invariant per-block row vectors (c and r for our 2 columns)
    const float4 cva = *(const float4*)&Cp[jb * L + ab];
    const float4 cvb = *(const float4*)&Cp[(jb + 1) * L + ab];
    const float4 rva = *(const float4*)&Rp[jb * L + ab];
    const float4 rvb = *(const float4*)&Rp[(jb + 1) * L + ab];
    const float ca[4] = {cva.x, cva.y, cva.z, cva.w};
    const float cb[4] = {cvb.x, cvb.y, cvb.z, cvb.w};
    const float ra[4] = {rva.x, rva.y, rva.z, rva.w};
    const float rb[4] = {rvb.x, rvb.y, rvb.z, rvb.w};

    for (int idx = tid; idx < 4096; idx += 512) Uc[idx] = 1.0f / L;
    __syncthreads();

    float acc[4][2];

    auto stage = [&](const float* Mg, int b0, int buf) {
        const char* g = (const char*)Mg + (size_t)b0 * 1024 + gcol;
        char* l = lbase + (buf << 11);
        GLL16(g + ((o0 >> 7) << 10) + (o0 & 127), l + o0);
        GLL16(g + ((o1 >> 7) << 10) + (o1 & 127), l + o1);
    };

    auto run_pass = [&](const float* __restrict__ Mg, const float* __restrict__ S) {
#pragma unroll
        for (int ai = 0; ai < 4; ai++) { acc[ai][0] = 0.f; acc[ai][1] = 0.f; }
        stage(Mg, 0, 0);
        for (int t = 0; t < 16; t++) {
            WAITLGKM0();                 // our prior-tile ds_reads fully drained
            if (t < 15) {
                stage(Mg, (t + 1) * 16, (t + 1) & 1);
                WAITVM2();               // tile t's two loads have landed
            } else {
                WAITVM0();
            }
            const float* Kb = &Kw[w * 1024 + ((t & 1) << 9)] + ta * 4;
            const float* St = S + (t << 8);
#pragma unroll
            for (int bbi = 0; bbi < 16; bbi++) {
                float4 kv = *(const float4*)&Kb[bbi * 32];
                float2 sv = *(const float2*)&St[bbi * 16 + (jb ^ (bbi & 14))];
                acc[0][0] = fmaf(kv.x, sv.x, acc[0][0]); acc[0][1] = fmaf(kv.x, sv.y, acc[0][1]);
                acc[1][0] = fmaf(kv.y, sv.x, acc[1][0]); acc[1][1] = fmaf(kv.y, sv.y, acc[1][1]);
                acc[2][0] = fmaf(kv.z, sv.x, acc[2][0]); acc[2][1] = fmaf(kv.z, sv.y, acc[2][1]);
                acc[3][0] = fmaf(kv.w, sv.x, acc[3][0]); acc[3][1] = fmaf(kv.w, sv.y, acc[3][1]);
            }
        }
    };

    float lp = 0.f;
    for (int it = 0; it < NITER; it++) {
        // pass A: acc = K @ U ; T = c/(acc+eps)
        run_pass(Kp, Uc);
#pragma unroll
        for (int ai = 0; ai < 4; ai++) {
            const int bI = ab + ai;
            float2 o;
            o.x = ca[ai] / (acc[ai][0] + EPSF);
            o.y = cb[ai] / (acc[ai][1] + EPSF);
            *(float2*)&Tc[bI * 16 + (jb ^ (bI & 14))] = o;
        }
        __syncthreads();
        // pass B: acc = K @ T ; U = r/(acc+eps)
        run_pass(Kp, Tc);
#pragma unroll
        for (int ai = 0; ai < 4; ai++) {
            const int bI = ab + ai;
            float2 o;
            o.x = ra[ai] / (acc[ai][0] + EPSF);
            o.y = rb[ai] / (acc[ai][1] + EPSF);
            *(float2*)&Uc[bI * 16 + (jb ^ (bI & 14))] = o;
        }
        __syncthreads();
    }
    // final V pass: V = c/(K@U+eps) -> Tc
    run_pass(Kp, Uc);
#pragma unroll
    for (int ai = 0; ai < 4; ai++) {
        const int bI = ab + ai;
        float2 o;
        o.x = ca[ai] / (acc[ai][0] + EPSF);
        o.y = cb[ai] / (acc[ai][1] + EPSF);
        *(float2*)&Tc[bI * 16 + (jb ^ (bI & 14))] = o;
    }
    __syncthreads();
    // loss pass: acc = KM @ V ; lp += sum U*acc
    run_pass(KMp, Tc);
#pragma unroll
    for (int ai = 0; ai < 4; ai++) {
        const int bI = ab + ai;
#pragma unroll
        for (int cj = 0; cj < 2; cj++)
            lp += Uc[bI * 16 + ((jb + cj) ^ (bI & 14))] * acc[ai][cj];
    }
    __syncthreads();
    // block reduction (reuse Kw as scratch — staging all drained)
    float* red = Kw;
    red[tid] = lp;
    __syncthreads();
    for (int o = 256; o >= 1; o >>= 1) {
        if (tid < o) red[tid] += red[tid + o];
        __syncthreads();
    }
    if (tid == 0) lossbuf[bid] = red[0];
}

// ---------------------------------------------------------------------------
// K7: final sum  (unchanged)
// ---------------------------------------------------------------------------
__global__ __launch_bounds__(256) void k_final(
    const float* __restrict__ lossbuf, float* __restrict__ out)
{
    __shared__ float red[256];
    int t = threadIdx.x;
    red[t] = lossbuf[t];
    __syncthreads();
    for (int o = 128; o >= 1; o >>= 1) {
        if (t < o) red[t] += red[t + o];
        __syncthreads();
    }
    if (t == 0) out[0] = red[0];
}

extern "C" void kernel_launch(void* const* d_in, const int* in_sizes, int n_in,
                              void* d_out, int out_size, void* d_ws, size_t ws_size,
                              hipStream_t stream)
{
    const float* f    = (const float*)d_in[0];
    const float* head = (const float*)d_in[1];
    const float* W1   = (const float*)d_in[2];
    const float* b1   = (const float*)d_in[3];
    const float* W2   = (const float*)d_in[4];
    const float* b2   = (const float*)d_in[5];
    float* scores = (float*)d_out;
    float* wloss  = scores + (long)NB * L * L;

    float* ws      = (float*)d_ws;
    float* C       = ws;
    float* Km      = ws + 1 * 1048576;
    float* KMm     = ws + 2 * 1048576;
    float* R       = ws + 3 * 1048576;
    float* Cd      = ws + 4 * 1048576;
    float* maxabs  = ws + 5 * 1048576;
    float* lossbuf = maxabs + 64;

    k_scores<<<16384, 256, 0, stream>>>(f, W1, b1, W2, b2, scores);
    k_cost  <<<4096,  256, 0, stream>>>(f, C);
    k_absmax<<<NB,    256, 0, stream>>>(C, maxabs);
    k_kmat  <<<2048,  512, 0, stream>>>(C, maxabs, Km, KMm);
    k_rc    <<<NB * L, 256, 0, stream>>>(scores, head, R, Cd);
    k_sink  <<<NB * 16, 512, 0, stream>>>(Km, KMm, R, Cd, lossbuf);
    k_final <<<1, 256, 0, stream>>>(lossbuf, wloss);
}